// Round 2
// baseline (1681.789 us; speedup 1.0000x reference)
//
#include <hip/hip_runtime.h>
#include <hip/hip_bf16.h>

// GraphEncoder: NNConv (edge-MLP 16->256->1024->1024 + einsum + scatter) + 3x GINConv.
// R8: 1611us. enn-L3 gemm chunks @149.8us = 611 TF (24% peak), MfmaUtil 27%,
// VALUBusy 52%, LDS bank-conflict 1.1e7, HBM 14% -> structural stall (vmcnt(0) drain
// at every __syncthreads, 16/32-bank LDS reads).
// R9 (container failed; schedule re-audited, no hazard found): gemm256 for enn-L2/L3:
// 256x256 tile, BK=32, 8 waves (2Mx4N, 128x64/wave), triple-buffered LDS (96KB),
// depth-2 prefetch, ONE counted s_waitcnt vmcnt(4) + ONE raw s_barrier per K-tile,
// XOR-swizzled LDS (write: pre-swizzled global col + linear global_load_lds dest;
// read: slot quad^((row>>1)&3)), setprio(1) around the 32-MFMA cluster.
// R10: resubmit with __launch_bounds__(512) (dropped contradictory ",2" min-waves
// claim: 96KB LDS only admits 1 block/CU). Everything else identical to R9.

#define NN 50000
#define EE 200000

typedef unsigned short u16;
typedef __attribute__((ext_vector_type(8))) short frag8;
typedef __attribute__((ext_vector_type(4))) float f32x4;

__device__ __forceinline__ float bf2f(u16 u) {
    union { unsigned int i; float f; } v; v.i = ((unsigned int)u) << 16; return v.f;
}
__device__ __forceinline__ u16 f2bf(float f) {
    union { float f; unsigned int i; } v; v.f = f;
    return (u16)((v.i + 0x7fffu + ((v.i >> 16) & 1u)) >> 16);
}
__device__ __forceinline__ float eluf(float v) {
    return v > 0.f ? v : __expf(v) - 1.f;
}

// ---------------- float dtype probe: fp32-as-bf16 shows crazy exponents ----------------
__global__ void probe_f32(const u16* __restrict__ raw, int* __restrict__ cnt) {
    int t = threadIdx.x;  // single block of 256
    int c = 0;
    for (int j = t; j < 1024; j += 256) {
        unsigned e = (raw[j] >> 7) & 0xFF;
        if (e >= 0xBF) c++;   // |v| >= 2^64: never in genuine N(0,1)-ish bf16 data
    }
    if (c) atomicAdd(cnt, c);
}
// dst bf16 <- src (fp32 if *cnt>=8 else bf16 passthrough)
__global__ void cvt_bf16(const void* __restrict__ src, u16* __restrict__ dst, long n,
                         const int* __restrict__ cnt) {
    long i = (long)blockIdx.x * 256 + threadIdx.x;
    if (i >= n) return;
    if (*cnt >= 8) dst[i] = f2bf(((const float*)src)[i]);
    else           dst[i] = ((const u16*)src)[i];
}

// ---------------- edge_index layout probe + conversion ----------------
__global__ void detect_idx64(const unsigned long long* __restrict__ p, int* __restrict__ flag) {
    long t = (long)blockIdx.x * 256 + threadIdx.x;
    if (t < EE) {
        unsigned long long v = p[t];
        if (v >> 31) atomicOr(flag, 1);   // int32-packed pairs have high bits set
    }
}
__global__ void convert_idx(const void* __restrict__ raw, const int* __restrict__ flag,
                            int* __restrict__ s_out, int* __restrict__ d_out) {
    long t = (long)blockIdx.x * 256 + threadIdx.x;
    if (t >= EE) return;
    if (*flag) {  // int32 layout
        const int* q = (const int*)raw;
        s_out[t] = q[t];
        d_out[t] = q[EE + t];
    } else {      // int64 layout
        const long long* q = (const long long*)raw;
        s_out[t] = (int)q[t];
        d_out[t] = (int)q[EE + t];
    }
}

// ---------------- generic bf16 transpose [K,N] -> [N,K] ----------------
__global__ void transpose_bf16(const u16* __restrict__ in, u16* __restrict__ out, int K, int N) {
    long idx = (long)blockIdx.x * 256 + threadIdx.x;
    if (idx < (long)K * N) {
        int k = (int)(idx / N);
        int n = (int)(idx % N);
        out[(long)n * K + k] = in[idx];
    }
}

// ---------------- edge MLP layer 1: h1 = ELU(attr @ W1 + b1), K=16, N=256 ----------------
__global__ void edge_mlp1(const u16* __restrict__ attr, const u16* __restrict__ w1,
                          const u16* __restrict__ b1, u16* __restrict__ h1, int ce) {
    __shared__ u16 sa[256];
    const int t = threadIdx.x;
    const int e0 = blockIdx.x * 16;
    const int cnt = min(16, ce - e0);
    sa[t] = (t < cnt * 16) ? attr[(long)e0 * 16 + t] : (u16)0;
    float w[16];
    #pragma unroll
    for (int i = 0; i < 16; ++i) w[i] = bf2f(w1[i * 256 + t]);
    const float bb = bf2f(b1[t]);
    __syncthreads();
    for (int e = 0; e < cnt; ++e) {
        float v = bb;
        #pragma unroll
        for (int i = 0; i < 16; ++i) v += bf2f(sa[e * 16 + i]) * w[i];
        h1[(long)(e0 + e) * 256 + t] = f2bf(eluf(v));
    }
}

// ---- stage 128x32 bf16 tile via global_load_lds (old 128^2 path, GIN g1/g2) ----
__device__ __forceinline__ void stage_tile(const u16* g, long row_base, long max_row,
                                           int kstride, int k0, u16* s, int t) {
    int wave = t >> 6;
    #pragma unroll
    for (int j = 0; j < 2; ++j) {
        int c = t + 256 * j;                 // chunk id 0..511 (16B each)
        long r = row_base + (c >> 2);        // 4 chunks per 32-elem row
        if (r > max_row) r = max_row;        // tail clamp (masked at C store)
        const u16* gp = g + r * (long)kstride + k0 + (c & 3) * 8;
        __builtin_amdgcn_global_load_lds(
            (__attribute__((address_space(1))) void*)(void*)gp,
            (__attribute__((address_space(3))) void*)((char*)s + wave * 1024 + j * 4096),
            16, 0, 0);                       // HW writes LDS at base + lane*16
    }
}

// C = ELU(A[M,K] @ BT[N,K]^T + bias), bf16 out. N mult of 128, K mult of 32.
// XCD-swizzled 1D grid. Kept for GIN g1/g2 (N=256, small FLOPs).
__global__ __launch_bounds__(256)
void gemm_bt_bias_elu(const u16* __restrict__ A, const u16* __restrict__ BT,
                      const u16* __restrict__ bias, u16* __restrict__ C,
                      int M, int K, int N, int mpx, int lognt) {
    const int bid = blockIdx.x;
    const int xcd = bid & 7;
    const int j = bid >> 3;
    const int m_idx = xcd * mpx + (j >> lognt);
    const int n_idx = j & ((1 << lognt) - 1);
    const int num_m = (M + 127) >> 7;
    if (m_idx >= num_m) return;              // block-uniform; before any barrier

    __shared__ __align__(16) u16 sA[128 * 32];
    __shared__ __align__(16) u16 sB[128 * 32];
    const int t = threadIdx.x;
    const int lane = t & 63;
    const int wave = t >> 6;
    const int wr = wave >> 1, wc = wave & 1;
    const int quad = lane >> 4, l16 = lane & 15;
    const long m0 = (long)m_idx * 128;
    const int n0 = n_idx * 128;

    f32x4 acc[4][4];
    const f32x4 z4 = {0.f, 0.f, 0.f, 0.f};
    #pragma unroll
    for (int mi = 0; mi < 4; ++mi)
        #pragma unroll
        for (int ni = 0; ni < 4; ++ni)
            acc[mi][ni] = z4;

    for (int k0 = 0; k0 < K; k0 += 32) {
        stage_tile(A, m0, (long)M - 1, K, k0, sA, t);
        stage_tile(BT, n0, (long)N - 1, K, k0, sB, t);
        __syncthreads();
        frag8 af[4], bfv[4];
        #pragma unroll
        for (int mi = 0; mi < 4; ++mi)
            af[mi] = *(const frag8*)(sA + (wr * 64 + mi * 16 + l16) * 32 + quad * 8);
        #pragma unroll
        for (int ni = 0; ni < 4; ++ni)
            bfv[ni] = *(const frag8*)(sB + (wc * 64 + ni * 16 + l16) * 32 + quad * 8);
        #pragma unroll
        for (int mi = 0; mi < 4; ++mi)
            #pragma unroll
            for (int ni = 0; ni < 4; ++ni)
                acc[mi][ni] = __builtin_amdgcn_mfma_f32_16x16x32_bf16(af[mi], bfv[ni], acc[mi][ni], 0, 0, 0);
        __syncthreads();
    }

    #pragma unroll
    for (int mi = 0; mi < 4; ++mi) {
        #pragma unroll
        for (int r = 0; r < 4; ++r) {
            long row = m0 + wr * 64 + mi * 16 + quad * 4 + r;  // C/D: row = quad*4+reg
            if (row < M) {
                #pragma unroll
                for (int ni = 0; ni < 4; ++ni) {
                    int col = n0 + wc * 64 + ni * 16 + l16;    // C/D: col = lane&15
                    float v = acc[mi][ni][r] + bf2f(bias[col]);
                    C[row * (long)N + col] = f2bf(eluf(v));
                }
            }
        }
    }
}

// R10: 256x256 tile, BK=32, 512 threads (8 waves = 2M x 4N, 128x64 out each).
// Triple-buffered LDS (3x16KB per matrix = 96KB), depth-2 prefetch: iter kt computes
// buf kt%3 while tiles kt+1,kt+2 are in flight. ONE counted vmcnt(4) + ONE raw
// s_barrier per K-tile; vmcnt never drains to 0 except the last iteration.
// LDS XOR-swizzle: read slot = quad^((row>>1)&3); write side via pre-swizzled global
// column slot' = (lane&3)^((row_in_chunk>>1)&3) with linear global_load_lds dest.
// Stage for kt+2 issued AFTER the kt barrier -> no WAR on buffer (kt-1)%3.
__global__ __launch_bounds__(512)
void gemm256(const u16* __restrict__ A, const u16* __restrict__ BT,
             const u16* __restrict__ bias, u16* __restrict__ C,
             int M, int K, int N, int mpx, int lognt) {
    const int bid = blockIdx.x;
    const int xcd = bid & 7;
    const int j = bid >> 3;
    const int m_idx = xcd * mpx + (j >> lognt);
    const int n_idx = j & ((1 << lognt) - 1);
    const int num_m = (M + 255) >> 8;
    if (m_idx >= num_m) return;              // block-uniform; before any barrier

    __shared__ __align__(16) u16 sA[3][256 * 32];
    __shared__ __align__(16) u16 sB[3][256 * 32];
    const int t = threadIdx.x;
    const int lane = t & 63;
    const int wave = t >> 6;          // 0..7
    const int wm = wave >> 2;         // 0..1 : M half (128 rows)
    const int wn = wave & 3;          // 0..3 : N quarter (64 cols)
    const int quad = lane >> 4, l16 = lane & 15;
    const long m0 = (long)m_idx * 256;
    const int n0 = n_idx * 256;

    // staging: chunk ck = wave*2+jj covers 16 rows (1024B); lane -> row +lane>>2,
    // LDS 16B-slot lane&3; GLOBAL col pre-swizzled so the swizzled read finds (row,k).
    const int rowin = lane >> 2;
    const int slotp = (((lane & 3) ^ ((lane >> 3) & 3)) << 3);  // elem offset 0/8/16/24

    // swizzled read base offsets (bytes); frag mi lives at +mi*1024
    const int rsw = (quad ^ ((l16 >> 1) & 3)) << 4;
    const int aoff = (wm * 128 + l16) * 64 + rsw;
    const int boff = (wn * 64 + l16) * 64 + rsw;

    const int ntk = K >> 5;

    auto stage = [&](int kt, int bf_) {
        #pragma unroll
        for (int jj = 0; jj < 2; ++jj) {
            const int ck = wave * 2 + jj;
            long r = m0 + ck * 16 + rowin;
            if (r > (long)M - 1) r = (long)M - 1;   // tail clamp, masked at C store
            const u16* gp = A + r * (long)K + (kt << 5) + slotp;
            __builtin_amdgcn_global_load_lds(
                (__attribute__((address_space(1))) void*)(void*)gp,
                (__attribute__((address_space(3))) void*)((char*)sA[bf_] + ck * 1024),
                16, 0, 0);
        }
        #pragma unroll
        for (int jj = 0; jj < 2; ++jj) {
            const int ck = wave * 2 + jj;
            long r = n0 + ck * 16 + rowin;
            if (r > (long)N - 1) r = (long)N - 1;
            const u16* gp = BT + r * (long)K + (kt << 5) + slotp;
            __builtin_amdgcn_global_load_lds(
                (__attribute__((address_space(1))) void*)(void*)gp,
                (__attribute__((address_space(3))) void*)((char*)sB[bf_] + ck * 1024),
                16, 0, 0);
        }
    };

    f32x4 acc[8][4];
    const f32x4 z4 = {0.f, 0.f, 0.f, 0.f};
    #pragma unroll
    for (int mi = 0; mi < 8; ++mi)
        #pragma unroll
        for (int ni = 0; ni < 4; ++ni)
            acc[mi][ni] = z4;

    stage(0, 0);                 // 4 loads/thread
    if (ntk > 1) stage(1, 1);    // 4 more -> 8 outstanding

    int buf = 0;
    for (int kt = 0; kt < ntk; ++kt) {
        // tile kt's 4 loads are the oldest; <=4 remaining => they landed (in-order retire).
        if (kt + 1 < ntk) asm volatile("s_waitcnt vmcnt(4)" ::: "memory");
        else              asm volatile("s_waitcnt vmcnt(0)" ::: "memory");
        __builtin_amdgcn_s_barrier();          // all waves' tile-kt data visible
        __builtin_amdgcn_sched_barrier(0);     // nothing crosses the barrier
        if (kt + 2 < ntk) stage(kt + 2, buf == 0 ? 2 : buf - 1);  // buffer (kt+2)%3

        const u16* pa = sA[buf];
        const u16* pb = sB[buf];
        frag8 af[8], bfv[4];
        #pragma unroll
        for (int mi = 0; mi < 8; ++mi)
            af[mi] = *(const frag8*)((const char*)pa + aoff + mi * 1024);
        #pragma unroll
        for (int ni = 0; ni < 4; ++ni)
            bfv[ni] = *(const frag8*)((const char*)pb + boff + ni * 1024);
        __builtin_amdgcn_s_setprio(1);
        #pragma unroll
        for (int mi = 0; mi < 8; ++mi)
            #pragma unroll
            for (int ni = 0; ni < 4; ++ni)
                acc[mi][ni] = __builtin_amdgcn_mfma_f32_16x16x32_bf16(af[mi], bfv[ni], acc[mi][ni], 0, 0, 0);
        __builtin_amdgcn_s_setprio(0);
        buf = (buf == 2) ? 0 : buf + 1;
    }

    #pragma unroll
    for (int mi = 0; mi < 8; ++mi) {
        #pragma unroll
        for (int r = 0; r < 4; ++r) {
            long row = m0 + wm * 128 + mi * 16 + quad * 4 + r;   // C/D: row = quad*4+reg
            if (row < M) {
                #pragma unroll
                for (int ni = 0; ni < 4; ++ni) {
                    int col = n0 + wn * 64 + ni * 16 + l16;      // C/D: col = lane&15
                    float v = acc[mi][ni][r] + bf2f(bias[col]);
                    C[row * (long)N + col] = f2bf(eluf(v));
                }
            }
        }
    }
}

// C[M,64] fp32 = A[M,K] @ BT[64,K]^T + bias (no ELU). M-tile 256, N=64, K mult of 32.
__global__ __launch_bounds__(256)
void gemm_bt_f32(const u16* __restrict__ A, const u16* __restrict__ BT,
                 const u16* __restrict__ bias, float* __restrict__ C,
                 int M, int K) {
    __shared__ __align__(16) u16 sA[256 * 32];
    __shared__ __align__(16) u16 sB[64 * 32];
    const int t = threadIdx.x;
    const int lane = t & 63;
    const int wave = t >> 6;
    const int quad = lane >> 4, l16 = lane & 15;
    const long m0 = (long)blockIdx.x * 256;

    f32x4 acc[4][4];
    const f32x4 z4 = {0.f, 0.f, 0.f, 0.f};
    #pragma unroll
    for (int mi = 0; mi < 4; ++mi)
        #pragma unroll
        for (int ni = 0; ni < 4; ++ni)
            acc[mi][ni] = z4;

    for (int k0 = 0; k0 < K; k0 += 32) {
        #pragma unroll
        for (int j = 0; j < 4; ++j) {
            int c = t + 256 * j;
            long r = m0 + (c >> 2);
            if (r > (long)M - 1) r = (long)M - 1;
            const u16* gp = A + r * (long)K + k0 + (c & 3) * 8;
            __builtin_amdgcn_global_load_lds(
                (__attribute__((address_space(1))) void*)(void*)gp,
                (__attribute__((address_space(3))) void*)((char*)sA + wave * 1024 + j * 4096),
                16, 0, 0);
        }
        {
            int c = t;
            const u16* gp = BT + (long)(c >> 2) * K + k0 + (c & 3) * 8;
            __builtin_amdgcn_global_load_lds(
                (__attribute__((address_space(1))) void*)(void*)gp,
                (__attribute__((address_space(3))) void*)((char*)sB + wave * 1024),
                16, 0, 0);
        }
        __syncthreads();
        frag8 af[4], bfv[4];
        #pragma unroll
        for (int mi = 0; mi < 4; ++mi)
            af[mi] = *(const frag8*)(sA + (wave * 64 + mi * 16 + l16) * 32 + quad * 8);
        #pragma unroll
        for (int ni = 0; ni < 4; ++ni)
            bfv[ni] = *(const frag8*)(sB + (ni * 16 + l16) * 32 + quad * 8);
        #pragma unroll
        for (int mi = 0; mi < 4; ++mi)
            #pragma unroll
            for (int ni = 0; ni < 4; ++ni)
                acc[mi][ni] = __builtin_amdgcn_mfma_f32_16x16x32_bf16(af[mi], bfv[ni], acc[mi][ni], 0, 0, 0);
        __syncthreads();
    }

    #pragma unroll
    for (int mi = 0; mi < 4; ++mi) {
        #pragma unroll
        for (int r = 0; r < 4; ++r) {
            long row = m0 + wave * 64 + mi * 16 + quad * 4 + r;
            if (row < M) {
                #pragma unroll
                for (int ni = 0; ni < 4; ++ni) {
                    int col = ni * 16 + l16;
                    C[row * 64 + col] = acc[mi][ni][r] + bf2f(bias[col]);
                }
            }
        }
    }
}

// msg[e,o] = sum_i x[src[e],i] * we[e, i*64+o]; atomicAdd into agg[dst[e],o]
__global__ void nnconv_msg(const u16* __restrict__ we, const u16* __restrict__ x,
                           const int* __restrict__ src, const int* __restrict__ dst,
                           float* __restrict__ agg, int ce) {
    long idx = (long)blockIdx.x * 256 + threadIdx.x;
    if (idx >= (long)ce * 64) return;
    int o = (int)(idx & 63);
    long e = idx >> 6;
    const u16* wr = we + e * 1024;
    const u16* xr = x + (long)src[e] * 16;
    float v = 0.f;
    #pragma unroll
    for (int i = 0; i < 16; ++i)
        v += bf2f(xr[i]) * bf2f(wr[i * 64 + o]);
    atomicAdd(&agg[(long)dst[e] * 64 + o], v);
}

// ---- x_cur(emb0) = x @ root_w + root_b + agg (in-place on agg) ----
__global__ void add_root(const u16* __restrict__ x, const u16* __restrict__ rw,
                         const u16* __restrict__ rb, float* __restrict__ xcur) {
    long idx = (long)blockIdx.x * 256 + threadIdx.x;
    if (idx >= (long)NN * 64) return;
    int d = (int)(idx & 63);
    long n = idx >> 6;
    float v = bf2f(rb[d]);
    #pragma unroll
    for (int i = 0; i < 16; ++i)
        v += bf2f(x[n * 16 + i]) * bf2f(rw[i * 64 + d]);
    xcur[idx] += v;
}

__global__ void elu_bf16(const float* __restrict__ in, u16* __restrict__ o, long n) {
    long idx = (long)blockIdx.x * 256 + threadIdx.x;
    if (idx < n) o[idx] = f2bf(eluf(in[idx]));
}

__global__ void gin_scatter(const u16* __restrict__ xin, const int* __restrict__ src,
                            const int* __restrict__ dst, float* __restrict__ nbr) {
    long idx = (long)blockIdx.x * 256 + threadIdx.x;
    if (idx >= (long)EE * 64) return;
    int d = (int)(idx & 63);
    long e = idx >> 6;
    atomicAdd(&nbr[(long)dst[e] * 64 + d], bf2f(xin[(long)src[e] * 64 + d]));
}

__global__ void gin_combine(const u16* __restrict__ xin, const float* __restrict__ nbr,
                            u16* __restrict__ hin, long n) {
    long idx = (long)blockIdx.x * 256 + threadIdx.x;
    if (idx < n) hin[idx] = f2bf(bf2f(xin[idx]) + nbr[idx]);
}

// out[n,d,l] = emb_l[n*64+d] -- one float4 per (n,d), fully coalesced
__global__ void write_out(const float* __restrict__ e0, const float* __restrict__ e1,
                          const float* __restrict__ e2, const float* __restrict__ e3,
                          float* __restrict__ out) {
    long idx = (long)blockIdx.x * 256 + threadIdx.x;
    if (idx >= (long)NN * 64) return;
    float4 v = {e0[idx], e1[idx], e2[idx], e3[idx]};
    *(float4*)(out + idx * 4) = v;
}

extern "C" void kernel_launch(void* const* d_in, const int* in_sizes, int n_in,
                              void* d_out, int out_size, void* d_ws, size_t ws_size,
                              hipStream_t stream) {
    (void)in_sizes; (void)n_in; (void)out_size;
    const void* eidx = d_in[1];
    float* out = (float*)d_out;   // reference output dtype = float32

    char* ws = (char*)d_ws;
    size_t off = 0;
    auto alloc = [&](size_t bytes) {
        char* p = ws + off;
        off += (bytes + 255) & ~(size_t)255;
        return p;
    };
    // ---- persistent ----
    int* src32 = (int*)alloc((size_t)EE * 4);
    int* dst32 = (int*)alloc((size_t)EE * 4);
    int* flag  = (int*)alloc(256);
    int* cnt   = (int*)alloc(256);
    const int cv_idx[16] = {0, 2, 3, 4, 5, 6, 7, 8, 9, 10, 11, 12, 13, 14, 15, 16};
    const long cv_n[16]  = {800000, 3200000, 4096, 256, 262144, 1024, 1048576, 1024,
                            1024, 64, 49152, 768, 196608, 768, 49152, 192};
    u16* cv[16];
    for (int i = 0; i < 16; ++i) cv[i] = (u16*)alloc((size_t)cv_n[i] * 2);
    u16 *xc = cv[0], *eac = cv[1], *w1c = cv[2], *b1c = cv[3], *w2c = cv[4], *b2c = cv[5],
        *w3c = cv[6], *b3c = cv[7], *rwc = cv[8], *rbc = cv[9],
        *g1c = cv[10], *gb1c = cv[11], *g2c = cv[12], *gb2c = cv[13], *g3c = cv[14], *gb3c = cv[15];
    u16* w2t = (u16*)alloc((size_t)1024 * 256 * 2);
    u16* w3t = (u16*)alloc((size_t)1024 * 1024 * 2);
    u16* g1t = (u16*)alloc((size_t)3 * 256 * 64 * 2);
    u16* g2t = (u16*)alloc((size_t)3 * 256 * 256 * 2);
    u16* g3t = (u16*)alloc((size_t)3 * 64 * 256 * 2);
    // per-layer node embeddings, fp32 [N,64]; emb[0] doubles as agg/x_cur
    float* emb[4];
    for (int l = 0; l < 4; ++l) emb[l] = (float*)alloc((size_t)NN * 64 * 4);
    float* agg = emb[0];
    char* scratch = (char*)alloc(0);
    size_t avail = (ws_size > off + 4096) ? (ws_size - off - 4096) : 0;

    // ---- NNConv edge-chunk: h1c (512 B/e) + h2c (2048 B/e) + wec (2048 B/e) ----
    long CE = (long)(avail / 4608) & ~127L;
    if (CE < 128) CE = 128;
    if (CE > 200064) CE = 200064;
    u16* h1c = (u16*)scratch;
    u16* h2c = (u16*)(scratch + (size_t)CE * 512);
    u16* wec = (u16*)(scratch + (size_t)CE * 2560);

    // ---- GIN node-chunk: nbr+xin fixed (19.2MB) + 1152 B/node ----
    long gin_fixed = (long)NN * 64 * 4 + (long)NN * 64 * 2;
    long gin_avail = (long)avail - gin_fixed;
    if (gin_avail < 0) gin_avail = 0;
    long CN = (gin_avail / 1152) & ~255L;
    if (CN < 256) CN = 256;
    if (CN > 50176) CN = 50176;
    float* nbr = (float*)scratch;
    u16* xin   = (u16*)(scratch + (size_t)NN * 64 * 4);
    u16* hin   = (u16*)(scratch + gin_fixed);
    u16* hg1   = hin + (size_t)CN * 64;
    u16* hg2   = hg1 + (size_t)CN * 256;

    auto cdiv = [](long a, long b) { return (unsigned)((a + b - 1) / b); };

    // dtype probe on x, then normalize all float inputs to bf16
    hipMemsetAsync(cnt, 0, 4, stream);
    probe_f32<<<1, 256, 0, stream>>>((const u16*)d_in[0], cnt);
    for (int i = 0; i < 16; ++i)
        cvt_bf16<<<cdiv(cv_n[i], 256), 256, 0, stream>>>(d_in[cv_idx[i]], cv[i], cv_n[i], cnt);

    // edge_index conversion (layout-robust)
    hipMemsetAsync(flag, 0, 4, stream);
    detect_idx64<<<cdiv(EE, 256), 256, 0, stream>>>((const unsigned long long*)eidx, flag);
    convert_idx<<<cdiv(EE, 256), 256, 0, stream>>>(eidx, flag, src32, dst32);

    // weight transposes [K,N] -> [N,K]
    transpose_bf16<<<cdiv(256 * 1024, 256), 256, 0, stream>>>(w2c, w2t, 256, 1024);
    transpose_bf16<<<cdiv(1024 * 1024, 256), 256, 0, stream>>>(w3c, w3t, 1024, 1024);
    for (int l = 0; l < 3; ++l) {
        transpose_bf16<<<cdiv(64 * 256, 256), 256, 0, stream>>>(g1c + l * 64 * 256, g1t + l * 256 * 64, 64, 256);
        transpose_bf16<<<cdiv(256 * 256, 256), 256, 0, stream>>>(g2c + l * 256 * 256, g2t + l * 256 * 256, 256, 256);
        transpose_bf16<<<cdiv(256 * 64, 256), 256, 0, stream>>>(g3c + l * 256 * 64, g3t + l * 64 * 256, 256, 64);
    }

    // ---- NNConv (edge-chunked) ----
    hipMemsetAsync(agg, 0, (size_t)NN * 64 * 4, stream);
    for (long e0 = 0; e0 < EE; e0 += CE) {
        int ce = (int)((EE - e0 < CE) ? (EE - e0) : CE);
        int mpx2 = cdiv(cdiv(ce, 256), 8);
        edge_mlp1<<<cdiv(ce, 16), 256, 0, stream>>>(eac + e0 * 16, w1c, b1c, h1c, ce);
        gemm256<<<8 * mpx2 * 4, 512, 0, stream>>>(h1c, w2t, b2c, h2c, ce, 256, 1024, mpx2, 2);
        gemm256<<<8 * mpx2 * 4, 512, 0, stream>>>(h2c, w3t, b3c, wec, ce, 1024, 1024, mpx2, 2);
        nnconv_msg<<<cdiv((long)ce * 64, 256), 256, 0, stream>>>(wec, xc, src32 + e0, dst32 + e0, agg, ce);
    }
    add_root<<<cdiv((long)NN * 64, 256), 256, 0, stream>>>(xc, rwc, rbc, agg);

    // ---- 3x GINConv (node-chunked MLP) ----
    for (int l = 0; l < 3; ++l) {
        elu_bf16<<<cdiv((long)NN * 64, 256), 256, 0, stream>>>(emb[l], xin, (long)NN * 64);
        hipMemsetAsync(nbr, 0, (size_t)NN * 64 * 4, stream);
        gin_scatter<<<cdiv((long)EE * 64, 256), 256, 0, stream>>>(xin, src32, dst32, nbr);
        for (long n0 = 0; n0 < NN; n0 += CN) {
            int cn = (int)((NN - n0 < CN) ? (NN - n0) : CN);
            int mpx = cdiv(cdiv(cn, 128), 8);
            gin_combine<<<cdiv((long)cn * 64, 256), 256, 0, stream>>>(xin + n0 * 64, nbr + n0 * 64, hin, (long)cn * 64);
            gemm_bt_bias_elu<<<8 * mpx * 2, 256, 0, stream>>>(hin, g1t + l * 256 * 64, gb1c + l * 256, hg1, cn, 64, 256, mpx, 1);
            gemm_bt_bias_elu<<<8 * mpx * 2, 256, 0, stream>>>(hg1, g2t + l * 256 * 256, gb2c + l * 256, hg2, cn, 256, 256, mpx, 1);
            gemm_bt_f32<<<cdiv(cn, 256), 256, 0, stream>>>(hg2, g3t + l * 64 * 256, gb3c + l * 64, emb[l + 1] + n0 * 64, cn, 256);
        }
    }
    write_out<<<cdiv((long)NN * 64, 256), 256, 0, stream>>>(emb[0], emb[1], emb[2], emb[3], out);
}

// Round 4
// 1552.990 us; speedup vs baseline: 1.0829x; 1.0829x over previous
//
#include <hip/hip_runtime.h>
#include <hip/hip_bf16.h>

// GraphEncoder: NNConv (edge-MLP 16->256->1024->1024 + einsum + scatter) + 3x GINConv.
// R10: 1681us. gemm256 (enn-L3) 153us = 611 TF. Swizzle WORKED (bank conflicts
// 1.1e7 -> 0), VALUBusy 52->21.5, but MfmaUtil 24.7: 2-phase structural ceiling
// (m233: 607 TF) -- coarse {read-all, mfma-all} lockstep.
// R11 (container failed; launch-risk audit -> register budget): 8-phase schedule
// (m201 template): BK=64, 128KB LDS = 2 buf x {A0,A1,B0,B1} 16KB regions; per
// phase: ds_read subtile + stage ONE region + barrier + lgkmcnt(0) + setprio +
// 16 MFMA + barrier. vmcnt(4) only at phases 4/8.
// R12: add __launch_bounds__(512,2): an 8-wave block NEEDS 2 waves/SIMD, so the
// allocator must cap at 256 regs/lane (acc 128 AGPR + av/bv 64 + addresses was
// borderline); without the cap an over-allocation makes the block unlaunchable
// -> cascading launch failures. Everything else identical to R11.

#define NN 50000
#define EE 200000

typedef unsigned short u16;
typedef __attribute__((ext_vector_type(8))) short frag8;
typedef __attribute__((ext_vector_type(4))) float f32x4;

__device__ __forceinline__ float bf2f(u16 u) {
    union { unsigned int i; float f; } v; v.i = ((unsigned int)u) << 16; return v.f;
}
__device__ __forceinline__ u16 f2bf(float f) {
    union { float f; unsigned int i; } v; v.f = f;
    return (u16)((v.i + 0x7fffu + ((v.i >> 16) & 1u)) >> 16);
}
__device__ __forceinline__ float eluf(float v) {
    return v > 0.f ? v : __expf(v) - 1.f;
}

// ---------------- float dtype probe: fp32-as-bf16 shows crazy exponents ----------------
__global__ void probe_f32(const u16* __restrict__ raw, int* __restrict__ cnt) {
    int t = threadIdx.x;  // single block of 256
    int c = 0;
    for (int j = t; j < 1024; j += 256) {
        unsigned e = (raw[j] >> 7) & 0xFF;
        if (e >= 0xBF) c++;   // |v| >= 2^64: never in genuine N(0,1)-ish bf16 data
    }
    if (c) atomicAdd(cnt, c);
}
// dst bf16 <- src (fp32 if *cnt>=8 else bf16 passthrough)
__global__ void cvt_bf16(const void* __restrict__ src, u16* __restrict__ dst, long n,
                         const int* __restrict__ cnt) {
    long i = (long)blockIdx.x * 256 + threadIdx.x;
    if (i >= n) return;
    if (*cnt >= 8) dst[i] = f2bf(((const float*)src)[i]);
    else           dst[i] = ((const u16*)src)[i];
}

// ---------------- edge_index layout probe + conversion ----------------
__global__ void detect_idx64(const unsigned long long* __restrict__ p, int* __restrict__ flag) {
    long t = (long)blockIdx.x * 256 + threadIdx.x;
    if (t < EE) {
        unsigned long long v = p[t];
        if (v >> 31) atomicOr(flag, 1);   // int32-packed pairs have high bits set
    }
}
__global__ void convert_idx(const void* __restrict__ raw, const int* __restrict__ flag,
                            int* __restrict__ s_out, int* __restrict__ d_out) {
    long t = (long)blockIdx.x * 256 + threadIdx.x;
    if (t >= EE) return;
    if (*flag) {  // int32 layout
        const int* q = (const int*)raw;
        s_out[t] = q[t];
        d_out[t] = q[EE + t];
    } else {      // int64 layout
        const long long* q = (const long long*)raw;
        s_out[t] = (int)q[t];
        d_out[t] = (int)q[EE + t];
    }
}

// ---------------- generic bf16 transpose [K,N] -> [N,K] ----------------
__global__ void transpose_bf16(const u16* __restrict__ in, u16* __restrict__ out, int K, int N) {
    long idx = (long)blockIdx.x * 256 + threadIdx.x;
    if (idx < (long)K * N) {
        int k = (int)(idx / N);
        int n = (int)(idx % N);
        out[(long)n * K + k] = in[idx];
    }
}

// ---------------- edge MLP layer 1: h1 = ELU(attr @ W1 + b1), K=16, N=256 ----------------
__global__ void edge_mlp1(const u16* __restrict__ attr, const u16* __restrict__ w1,
                          const u16* __restrict__ b1, u16* __restrict__ h1, int ce) {
    __shared__ u16 sa[256];
    const int t = threadIdx.x;
    const int e0 = blockIdx.x * 16;
    const int cnt = min(16, ce - e0);
    sa[t] = (t < cnt * 16) ? attr[(long)e0 * 16 + t] : (u16)0;
    float w[16];
    #pragma unroll
    for (int i = 0; i < 16; ++i) w[i] = bf2f(w1[i * 256 + t]);
    const float bb = bf2f(b1[t]);
    __syncthreads();
    for (int e = 0; e < cnt; ++e) {
        float v = bb;
        #pragma unroll
        for (int i = 0; i < 16; ++i) v += bf2f(sa[e * 16 + i]) * w[i];
        h1[(long)(e0 + e) * 256 + t] = f2bf(eluf(v));
    }
}

// ---- stage 128x32 bf16 tile via global_load_lds (old 128^2 path, GIN g1/g2) ----
__device__ __forceinline__ void stage_tile(const u16* g, long row_base, long max_row,
                                           int kstride, int k0, u16* s, int t) {
    int wave = t >> 6;
    #pragma unroll
    for (int j = 0; j < 2; ++j) {
        int c = t + 256 * j;                 // chunk id 0..511 (16B each)
        long r = row_base + (c >> 2);        // 4 chunks per 32-elem row
        if (r > max_row) r = max_row;        // tail clamp (masked at C store)
        const u16* gp = g + r * (long)kstride + k0 + (c & 3) * 8;
        __builtin_amdgcn_global_load_lds(
            (__attribute__((address_space(1))) void*)(void*)gp,
            (__attribute__((address_space(3))) void*)((char*)s + wave * 1024 + j * 4096),
            16, 0, 0);                       // HW writes LDS at base + lane*16
    }
}

// C = ELU(A[M,K] @ BT[N,K]^T + bias), bf16 out. N mult of 128, K mult of 32.
// XCD-swizzled 1D grid. Kept for GIN g1/g2 (N=256, small FLOPs).
__global__ __launch_bounds__(256)
void gemm_bt_bias_elu(const u16* __restrict__ A, const u16* __restrict__ BT,
                      const u16* __restrict__ bias, u16* __restrict__ C,
                      int M, int K, int N, int mpx, int lognt) {
    const int bid = blockIdx.x;
    const int xcd = bid & 7;
    const int j = bid >> 3;
    const int m_idx = xcd * mpx + (j >> lognt);
    const int n_idx = j & ((1 << lognt) - 1);
    const int num_m = (M + 127) >> 7;
    if (m_idx >= num_m) return;              // block-uniform; before any barrier

    __shared__ __align__(16) u16 sA[128 * 32];
    __shared__ __align__(16) u16 sB[128 * 32];
    const int t = threadIdx.x;
    const int lane = t & 63;
    const int wave = t >> 6;
    const int wr = wave >> 1, wc = wave & 1;
    const int quad = lane >> 4, l16 = lane & 15;
    const long m0 = (long)m_idx * 128;
    const int n0 = n_idx * 128;

    f32x4 acc[4][4];
    const f32x4 z4 = {0.f, 0.f, 0.f, 0.f};
    #pragma unroll
    for (int mi = 0; mi < 4; ++mi)
        #pragma unroll
        for (int ni = 0; ni < 4; ++ni)
            acc[mi][ni] = z4;

    for (int k0 = 0; k0 < K; k0 += 32) {
        stage_tile(A, m0, (long)M - 1, K, k0, sA, t);
        stage_tile(BT, n0, (long)N - 1, K, k0, sB, t);
        __syncthreads();
        frag8 af[4], bfv[4];
        #pragma unroll
        for (int mi = 0; mi < 4; ++mi)
            af[mi] = *(const frag8*)(sA + (wr * 64 + mi * 16 + l16) * 32 + quad * 8);
        #pragma unroll
        for (int ni = 0; ni < 4; ++ni)
            bfv[ni] = *(const frag8*)(sB + (wc * 64 + ni * 16 + l16) * 32 + quad * 8);
        #pragma unroll
        for (int mi = 0; mi < 4; ++mi)
            #pragma unroll
            for (int ni = 0; ni < 4; ++ni)
                acc[mi][ni] = __builtin_amdgcn_mfma_f32_16x16x32_bf16(af[mi], bfv[ni], acc[mi][ni], 0, 0, 0);
        __syncthreads();
    }

    #pragma unroll
    for (int mi = 0; mi < 4; ++mi) {
        #pragma unroll
        for (int r = 0; r < 4; ++r) {
            long row = m0 + wr * 64 + mi * 16 + quad * 4 + r;  // C/D: row = quad*4+reg
            if (row < M) {
                #pragma unroll
                for (int ni = 0; ni < 4; ++ni) {
                    int col = n0 + wc * 64 + ni * 16 + l16;    // C/D: col = lane&15
                    float v = acc[mi][ni][r] + bf2f(bias[col]);
                    C[row * (long)N + col] = f2bf(eluf(v));
                }
            }
        }
    }
}

// ---------------- R12: 8-phase 256x256 GEMM (enn-L2/L3), BK=64 ----------------
// 512 thr = 8 waves (2M x 4N), per-wave out 128x64. LDS 128KB = buf{0,1} x
// regions {A0(rows 0-127), A1(128-255), B0(cols 0-127), B1(128-255)} x 16KB.
// Buf parity == K-tile parity (fixed). Each 16KB region: 128 rows x 64 k,
// row = 128B, 16B slots XOR-swizzled: LDS[row][s] holds global slot s^(row&7).
// Per phase: ds_read subtile + stage one region + barrier + lgkmcnt(0) +
// setprio + 16 MFMA + barrier. vmcnt(4) at phases 4 and 8 only.
//
// Region last-reader / stage-phase map (iter i; X=buf0 tile 2i, Y=buf1 2i+1;
// reads: ph1-4 on X, ph5-8 on Y):
//   ph1: st Y.A0<-2i+1   ph2: st Y.A1<-2i+1
//   ph3: st X.B0<-2i+2   ph4: st X.B1<-2i+2 + vmcnt(4) -> all of 2i+1 landed
//   ph5: st X.A0<-2i+2   ph6: st X.A1<-2i+2
//   ph7: st Y.B0<-2i+3   ph8: st Y.B1<-2i+3 + vmcnt(4) -> all of 2i+2 landed
// Last iter: tile idx clamps to ntk-1 -> dead writes into consumed regions.

#define QPHASE(PA, PB, QM, QN, LDA, LDB, STREG, SG, SRBASE, SRMAX, SKT, VMW)     \
  do {                                                                           \
    if (LDA) {                                                                   \
      _Pragma("unroll")                                                          \
      for (int mi = 0; mi < 4; ++mi) {                                           \
        _Pragma("unroll")                                                        \
        for (int kk = 0; kk < 2; ++kk) {                                         \
          int row = ((QM) * 4 + mi) * 16 + l16;                                  \
          int slot = ((kk << 2) + quad) ^ (l16 & 7);                             \
          av[mi][kk] = *(const frag8*)((const char*)(PA) + row * 128 + slot * 16); \
        }                                                                        \
      }                                                                          \
    }                                                                            \
    if ((LDB) >= 0) {                                                            \
      _Pragma("unroll")                                                          \
      for (int ni = 0; ni < 2; ++ni) {                                           \
        _Pragma("unroll")                                                        \
        for (int kk = 0; kk < 2; ++kk) {                                         \
          int row = (wn & 1) * 64 + (((LDB) & 1) * 2 + ni) * 16 + l16;           \
          int slot = ((kk << 2) + quad) ^ (l16 & 7);                             \
          bv[(LDB) & 1][ni][kk] =                                                \
              *(const frag8*)((const char*)(PB) + row * 128 + slot * 16);        \
        }                                                                        \
      }                                                                          \
    }                                                                            \
    stage((STREG), (SG), (SRBASE), (SRMAX), (SKT));                              \
    if (VMW) asm volatile("s_waitcnt vmcnt(4)" ::: "memory");                    \
    __builtin_amdgcn_s_barrier();                                                \
    asm volatile("s_waitcnt lgkmcnt(0)" ::: "memory");                           \
    __builtin_amdgcn_sched_barrier(0);                                           \
    __builtin_amdgcn_s_setprio(1);                                               \
    _Pragma("unroll")                                                            \
    for (int kk = 0; kk < 2; ++kk) {                                             \
      _Pragma("unroll")                                                          \
      for (int mi = 0; mi < 4; ++mi) {                                           \
        _Pragma("unroll")                                                        \
        for (int ni = 0; ni < 2; ++ni) {                                         \
          acc[(QM) * 4 + mi][(QN) * 2 + ni] =                                    \
              __builtin_amdgcn_mfma_f32_16x16x32_bf16(                           \
                  av[mi][kk], bv[(QN)][ni][kk],                                  \
                  acc[(QM) * 4 + mi][(QN) * 2 + ni], 0, 0, 0);                   \
        }                                                                        \
      }                                                                          \
    }                                                                            \
    __builtin_amdgcn_s_setprio(0);                                               \
    __builtin_amdgcn_s_barrier();                                                \
    __builtin_amdgcn_sched_barrier(0);                                           \
  } while (0)

__global__ __launch_bounds__(512, 2)
void gemm256p(const u16* __restrict__ A, const u16* __restrict__ BT,
              const u16* __restrict__ bias, u16* __restrict__ C,
              int M, int K, int N, int mpx, int lognt) {
    const int bid = blockIdx.x;
    const int xcd = bid & 7;
    const int j = bid >> 3;
    const int m_idx = xcd * mpx + (j >> lognt);
    const int n_idx = j & ((1 << lognt) - 1);
    const int num_m = (M + 255) >> 8;
    if (m_idx >= num_m) return;              // block-uniform; before any barrier

    __shared__ __align__(16) u16 lds[2][4][8192];  // [buf][A0,A1,B0,B1][16KB]
    const int t = threadIdx.x;
    const int lane = t & 63;
    const int wave = t >> 6;          // 0..7
    const int wm = wave >> 2;         // 0..1 : M half (128 rows)
    const int wn = wave & 3;          // 0..3 : N quarter (64 cols)
    const int quad = lane >> 4, l16 = lane & 15;
    const long m0 = (long)m_idx * 256;
    const long n0 = (long)n_idx * 256;

    // staging: chunk ck = wave*2+jj covers 8 rows (1KB); lane -> row ck*8+(lane>>3),
    // LDS 16B-slot lane&7; GLOBAL slot pre-swizzled: g = (lane&7) ^ ((lane>>3)&7)
    // == slot ^ (row&7)  -> read at slot g^(row&7) finds global slot g.
    const int gslot = (((lane & 7) ^ ((lane >> 3) & 7)) << 3);  // elem offset

    auto stage = [&](u16* reg, const u16* G, long rbase, long rmax, int kt) {
        #pragma unroll
        for (int jj = 0; jj < 2; ++jj) {
            const int ck = wave * 2 + jj;
            long r = rbase + ck * 8 + (lane >> 3);
            if (r > rmax) r = rmax;          // tail clamp, masked at C store
            const u16* gp = G + r * (long)K + ((long)kt << 6) + gslot;
            __builtin_amdgcn_global_load_lds(
                (__attribute__((address_space(1))) void*)(void*)gp,
                (__attribute__((address_space(3))) void*)((char*)reg + ck * 1024),
                16, 0, 0);
        }
    };

    f32x4 acc[8][4];
    const f32x4 z4 = {0.f, 0.f, 0.f, 0.f};
    #pragma unroll
    for (int mi = 0; mi < 8; ++mi)
        #pragma unroll
        for (int ni = 0; ni < 4; ++ni)
            acc[mi][ni] = z4;
    frag8 av[4][2];        // current A quadrant (4 m-subtiles x 2 kk)
    frag8 bv[2][2][2];     // both B sets [qn][ni][kk]

    const int ntk = K >> 6;          // K multiple of 128 -> ntk even
    const int niter = ntk >> 1;
    const long MM = (long)M - 1, NMX = (long)N - 1;

    // prologue: X <- tile0 (4 regions), Y.B <- tile1 (2 regions); 12 loads.
    stage(&lds[0][2][0], BT, n0,       NMX, 0);
    stage(&lds[0][3][0], BT, n0 + 128, NMX, 0);
    stage(&lds[0][0][0], A,  m0,       MM,  0);
    stage(&lds[0][1][0], A,  m0 + 128, MM,  0);
    stage(&lds[1][2][0], BT, n0,       NMX, 1);
    stage(&lds[1][3][0], BT, n0 + 128, NMX, 1);
    asm volatile("s_waitcnt vmcnt(4)" ::: "memory");   // tile0's 8 loads landed
    __builtin_amdgcn_s_barrier();

    const u16* paX = &lds[0][wm][0];
    const u16* pbX = &lds[0][2 + (wn >> 1)][0];
    const u16* paY = &lds[1][wm][0];
    const u16* pbY = &lds[1][2 + (wn >> 1)][0];

    for (int it = 0; it < niter; ++it) {
        const int t1k = 2 * it + 1;
        int t2k = 2 * it + 2; if (t2k > ntk - 1) t2k = ntk - 1;
        int t3k = 2 * it + 3; if (t3k > ntk - 1) t3k = ntk - 1;

        QPHASE(paX, pbX, 0, 0, 1,  0, &lds[1][0][0], A,  m0,       MM,  t1k, 0);
        QPHASE(paX, pbX, 0, 1, 0,  1, &lds[1][1][0], A,  m0 + 128, MM,  t1k, 0);
        QPHASE(paX, pbX, 1, 0, 1, -1, &lds[0][2][0], BT, n0,       NMX, t2k, 0);
        QPHASE(paX, pbX, 1, 1, 0, -1, &lds[0][3][0], BT, n0 + 128, NMX, t2k, 1);
        QPHASE(paY, pbY, 0, 0, 1,  0, &lds[0][0][0], A,  m0,       MM,  t2k, 0);
        QPHASE(paY, pbY, 0, 1, 0,  1, &lds[0][1][0], A,  m0 + 128, MM,  t2k, 0);
        QPHASE(paY, pbY, 1, 0, 1, -1, &lds[1][2][0], BT, n0,       NMX, t3k, 0);
        QPHASE(paY, pbY, 1, 1, 0, -1, &lds[1][3][0], BT, n0 + 128, NMX, t3k, 1);
    }
    asm volatile("s_waitcnt vmcnt(0)" ::: "memory");   // drain leftover stages

    #pragma unroll
    for (int mi = 0; mi < 8; ++mi) {
        #pragma unroll
        for (int r = 0; r < 4; ++r) {
            long row = m0 + wm * 128 + mi * 16 + quad * 4 + r;   // C/D: row = quad*4+reg
            if (row < M) {
                #pragma unroll
                for (int ni = 0; ni < 4; ++ni) {
                    long col = n0 + wn * 64 + ni * 16 + l16;     // C/D: col = lane&15
                    float v = acc[mi][ni][r] + bf2f(bias[col]);
                    C[row * (long)N + col] = f2bf(eluf(v));
                }
            }
        }
    }
}

// C[M,64] fp32 = A[M,K] @ BT[64,K]^T + bias (no ELU). M-tile 256, N=64, K mult of 32.
__global__ __launch_bounds__(256)
void gemm_bt_f32(const u16* __restrict__ A, const u16* __restrict__ BT,
                 const u16* __restrict__ bias, float* __restrict__ C,
                 int M, int K) {
    __shared__ __align__(16) u16 sA[256 * 32];
    __shared__ __align__(16) u16 sB[64 * 32];
    const int t = threadIdx.x;
    const int lane = t & 63;
    const int wave = t >> 6;
    const int quad = lane >> 4, l16 = lane & 15;
    const long m0 = (long)blockIdx.x * 256;

    f32x4 acc[4][4];
    const f32x4 z4 = {0.f, 0.f, 0.f, 0.f};
    #pragma unroll
    for (int mi = 0; mi < 4; ++mi)
        #pragma unroll
        for (int ni = 0; ni < 4; ++ni)
            acc[mi][ni] = z4;

    for (int k0 = 0; k0 < K; k0 += 32) {
        #pragma unroll
        for (int j = 0; j < 4; ++j) {
            int c = t + 256 * j;
            long r = m0 + (c >> 2);
            if (r > (long)M - 1) r = (long)M - 1;
            const u16* gp = A + r * (long)K + k0 + (c & 3) * 8;
            __builtin_amdgcn_global_load_lds(
                (__attribute__((address_space(1))) void*)(void*)gp,
                (__attribute__((address_space(3))) void*)((char*)sA + wave * 1024 + j * 4096),
                16, 0, 0);
        }
        {
            int c = t;
            const u16* gp = BT + (long)(c >> 2) * K + k0 + (c & 3) * 8;
            __builtin_amdgcn_global_load_lds(
                (__attribute__((address_space(1))) void*)(void*)gp,
                (__attribute__((address_space(3))) void*)((char*)sB + wave * 1024),
                16, 0, 0);
        }
        __syncthreads();
        frag8 af[4], bfv[4];
        #pragma unroll
        for (int mi = 0; mi < 4; ++mi)
            af[mi] = *(const frag8*)(sA + (wave * 64 + mi * 16 + l16) * 32 + quad * 8);
        #pragma unroll
        for (int ni = 0; ni < 4; ++ni)
            bfv[ni] = *(const frag8*)(sB + (ni * 16 + l16) * 32 + quad * 8);
        #pragma unroll
        for (int mi = 0; mi < 4; ++mi)
            #pragma unroll
            for (int ni = 0; ni < 4; ++ni)
                acc[mi][ni] = __builtin_amdgcn_mfma_f32_16x16x32_bf16(af[mi], bfv[ni], acc[mi][ni], 0, 0, 0);
        __syncthreads();
    }

    #pragma unroll
    for (int mi = 0; mi < 4; ++mi) {
        #pragma unroll
        for (int r = 0; r < 4; ++r) {
            long row = m0 + wave * 64 + mi * 16 + quad * 4 + r;
            if (row < M) {
                #pragma unroll
                for (int ni = 0; ni < 4; ++ni) {
                    int col = ni * 16 + l16;
                    C[row * 64 + col] = acc[mi][ni][r] + bf2f(bias[col]);
                }
            }
        }
    }
}

// msg[e,o] = sum_i x[src[e],i] * we[e, i*64+o]; atomicAdd into agg[dst[e],o]
__global__ void nnconv_msg(const u16* __restrict__ we, const u16* __restrict__ x,
                           const int* __restrict__ src, const int* __restrict__ dst,
                           float* __restrict__ agg, int ce) {
    long idx = (long)blockIdx.x * 256 + threadIdx.x;
    if (idx >= (long)ce * 64) return;
    int o = (int)(idx & 63);
    long e = idx >> 6;
    const u16* wr = we + e * 1024;
    const u16* xr = x + (long)src[e] * 16;
    float v = 0.f;
    #pragma unroll
    for (int i = 0; i < 16; ++i)
        v += bf2f(xr[i]) * bf2f(wr[i * 64 + o]);
    atomicAdd(&agg[(long)dst[e] * 64 + o], v);
}

// ---- x_cur(emb0) = x @ root_w + root_b + agg (in-place on agg) ----
__global__ void add_root(const u16* __restrict__ x, const u16* __restrict__ rw,
                         const u16* __restrict__ rb, float* __restrict__ xcur) {
    long idx = (long)blockIdx.x * 256 + threadIdx.x;
    if (idx >= (long)NN * 64) return;
    int d = (int)(idx & 63);
    long n = idx >> 6;
    float v = bf2f(rb[d]);
    #pragma unroll
    for (int i = 0; i < 16; ++i)
        v += bf2f(x[n * 16 + i]) * bf2f(rw[i * 64 + d]);
    xcur[idx] += v;
}

__global__ void elu_bf16(const float* __restrict__ in, u16* __restrict__ o, long n) {
    long idx = (long)blockIdx.x * 256 + threadIdx.x;
    if (idx < n) o[idx] = f2bf(eluf(in[idx]));
}

__global__ void gin_scatter(const u16* __restrict__ xin, const int* __restrict__ src,
                            const int* __restrict__ dst, float* __restrict__ nbr) {
    long idx = (long)blockIdx.x * 256 + threadIdx.x;
    if (idx >= (long)EE * 64) return;
    int d = (int)(idx & 63);
    long e = idx >> 6;
    atomicAdd(&nbr[(long)dst[e] * 64 + d], bf2f(xin[(long)src[e] * 64 + d]));
}

__global__ void gin_combine(const u16* __restrict__ xin, const float* __restrict__ nbr,
                            u16* __restrict__ hin, long n) {
    long idx = (long)blockIdx.x * 256 + threadIdx.x;
    if (idx < n) hin[idx] = f2bf(bf2f(xin[idx]) + nbr[idx]);
}

// out[n,d,l] = emb_l[n*64+d] -- one float4 per (n,d), fully coalesced
__global__ void write_out(const float* __restrict__ e0, const float* __restrict__ e1,
                          const float* __restrict__ e2, const float* __restrict__ e3,
                          float* __restrict__ out) {
    long idx = (long)blockIdx.x * 256 + threadIdx.x;
    if (idx >= (long)NN * 64) return;
    float4 v = {e0[idx], e1[idx], e2[idx], e3[idx]};
    *(float4*)(out + idx * 4) = v;
}

extern "C" void kernel_launch(void* const* d_in, const int* in_sizes, int n_in,
                              void* d_out, int out_size, void* d_ws, size_t ws_size,
                              hipStream_t stream) {
    (void)in_sizes; (void)n_in; (void)out_size;
    const void* eidx = d_in[1];
    float* out = (float*)d_out;   // reference output dtype = float32

    char* ws = (char*)d_ws;
    size_t off = 0;
    auto alloc = [&](size_t bytes) {
        char* p = ws + off;
        off += (bytes + 255) & ~(size_t)255;
        return p;
    };
    // ---- persistent ----
    int* src32 = (int*)alloc((size_t)EE * 4);
    int* dst32 = (int*)alloc((size_t)EE * 4);
    int* flag  = (int*)alloc(256);
    int* cnt   = (int*)alloc(256);
    const int cv_idx[16] = {0, 2, 3, 4, 5, 6, 7, 8, 9, 10, 11, 12, 13, 14, 15, 16};
    const long cv_n[16]  = {800000, 3200000, 4096, 256, 262144, 1024, 1048576, 1024,
                            1024, 64, 49152, 768, 196608, 768, 49152, 192};
    u16* cv[16];
    for (int i = 0; i < 16; ++i) cv[i] = (u16*)alloc((size_t)cv_n[i] * 2);
    u16 *xc = cv[0], *eac = cv[1], *w1c = cv[2], *b1c = cv[3], *w2c = cv[4], *b2c = cv[5],
        *w3c = cv[6], *b3c = cv[7], *rwc = cv[8], *rbc = cv[9],
        *g1c = cv[10], *gb1c = cv[11], *g2c = cv[12], *gb2c = cv[13], *g3c = cv[14], *gb3c = cv[15];
    u16* w2t = (u16*)alloc((size_t)1024 * 256 * 2);
    u16* w3t = (u16*)alloc((size_t)1024 * 1024 * 2);
    u16* g1t = (u16*)alloc((size_t)3 * 256 * 64 * 2);
    u16* g2t = (u16*)alloc((size_t)3 * 256 * 256 * 2);
    u16* g3t = (u16*)alloc((size_t)3 * 64 * 256 * 2);
    // per-layer node embeddings, fp32 [N,64]; emb[0] doubles as agg/x_cur
    float* emb[4];
    for (int l = 0; l < 4; ++l) emb[l] = (float*)alloc((size_t)NN * 64 * 4);
    float* agg = emb[0];
    char* scratch = (char*)alloc(0);
    size_t avail = (ws_size > off + 4096) ? (ws_size - off - 4096) : 0;

    // ---- NNConv edge-chunk: h1c (512 B/e) + h2c (2048 B/e) + wec (2048 B/e) ----
    long CE = (long)(avail / 4608) & ~127L;
    if (CE < 128) CE = 128;
    if (CE > 200064) CE = 200064;
    u16* h1c = (u16*)scratch;
    u16* h2c = (u16*)(scratch + (size_t)CE * 512);
    u16* wec = (u16*)(scratch + (size_t)CE * 2560);

    // ---- GIN node-chunk: nbr+xin fixed (19.2MB) + 1152 B/node ----
    long gin_fixed = (long)NN * 64 * 4 + (long)NN * 64 * 2;
    long gin_avail = (long)avail - gin_fixed;
    if (gin_avail < 0) gin_avail = 0;
    long CN = (gin_avail / 1152) & ~255L;
    if (CN < 256) CN = 256;
    if (CN > 50176) CN = 50176;
    float* nbr = (float*)scratch;
    u16* xin   = (u16*)(scratch + (size_t)NN * 64 * 4);
    u16* hin   = (u16*)(scratch + gin_fixed);
    u16* hg1   = hin + (size_t)CN * 64;
    u16* hg2   = hg1 + (size_t)CN * 256;

    auto cdiv = [](long a, long b) { return (unsigned)((a + b - 1) / b); };

    // dtype probe on x, then normalize all float inputs to bf16
    hipMemsetAsync(cnt, 0, 4, stream);
    probe_f32<<<1, 256, 0, stream>>>((const u16*)d_in[0], cnt);
    for (int i = 0; i < 16; ++i)
        cvt_bf16<<<cdiv(cv_n[i], 256), 256, 0, stream>>>(d_in[cv_idx[i]], cv[i], cv_n[i], cnt);

    // edge_index conversion (layout-robust)
    hipMemsetAsync(flag, 0, 4, stream);
    detect_idx64<<<cdiv(EE, 256), 256, 0, stream>>>((const unsigned long long*)eidx, flag);
    convert_idx<<<cdiv(EE, 256), 256, 0, stream>>>(eidx, flag, src32, dst32);

    // weight transposes [K,N] -> [N,K]
    transpose_bf16<<<cdiv(256 * 1024, 256), 256, 0, stream>>>(w2c, w2t, 256, 1024);
    transpose_bf16<<<cdiv(1024 * 1024, 256), 256, 0, stream>>>(w3c, w3t, 1024, 1024);
    for (int l = 0; l < 3; ++l) {
        transpose_bf16<<<cdiv(64 * 256, 256), 256, 0, stream>>>(g1c + l * 64 * 256, g1t + l * 256 * 64, 64, 256);
        transpose_bf16<<<cdiv(256 * 256, 256), 256, 0, stream>>>(g2c + l * 256 * 256, g2t + l * 256 * 256, 256, 256);
        transpose_bf16<<<cdiv(256 * 64, 256), 256, 0, stream>>>(g3c + l * 256 * 64, g3t + l * 64 * 256, 256, 64);
    }

    // ---- NNConv (edge-chunked) ----
    hipMemsetAsync(agg, 0, (size_t)NN * 64 * 4, stream);
    for (long e0 = 0; e0 < EE; e0 += CE) {
        int ce = (int)((EE - e0 < CE) ? (EE - e0) : CE);
        int mpx2 = cdiv(cdiv(ce, 256), 8);
        edge_mlp1<<<cdiv(ce, 16), 256, 0, stream>>>(eac + e0 * 16, w1c, b1c, h1c, ce);
        gemm256p<<<8 * mpx2 * 4, 512, 0, stream>>>(h1c, w2t, b2c, h2c, ce, 256, 1024, mpx2, 2);
        gemm256p<<<8 * mpx2 * 4, 512, 0, stream>>>(h2c, w3t, b3c, wec, ce, 1024, 1024, mpx2, 2);
        nnconv_msg<<<cdiv((long)ce * 64, 256), 256, 0, stream>>>(wec, xc, src32 + e0, dst32 + e0, agg, ce);
    }
    add_root<<<cdiv((long)NN * 64, 256), 256, 0, stream>>>(xc, rwc, rbc, agg);

    // ---- 3x GINConv (node-chunked MLP) ----
    for (int l = 0; l < 3; ++l) {
        elu_bf16<<<cdiv((long)NN * 64, 256), 256, 0, stream>>>(emb[l], xin, (long)NN * 64);
        hipMemsetAsync(nbr, 0, (size_t)NN * 64 * 4, stream);
        gin_scatter<<<cdiv((long)EE * 64, 256), 256, 0, stream>>>(xin, src32, dst32, nbr);
        for (long n0 = 0; n0 < NN; n0 += CN) {
            int cn = (int)((NN - n0 < CN) ? (NN - n0) : CN);
            int mpx = cdiv(cdiv(cn, 128), 8);
            gin_combine<<<cdiv((long)cn * 64, 256), 256, 0, stream>>>(xin + n0 * 64, nbr + n0 * 64, hin, (long)cn * 64);
            gemm_bt_bias_elu<<<8 * mpx * 2, 256, 0, stream>>>(hin, g1t + l * 256 * 64, gb1c + l * 256, hg1, cn, 64, 256, mpx, 1);
            gemm_bt_bias_elu<<<8 * mpx * 2, 256, 0, stream>>>(hg1, g2t + l * 256 * 256, gb2c + l * 256, hg2, cn, 256, 256, mpx, 1);
            gemm_bt_f32<<<cdiv(cn, 256), 256, 0, stream>>>(hg2, g3t + l * 64 * 256, gb3c + l * 64, emb[l + 1] + n0 * 64, cn, 256);
        }
    }
    write_out<<<cdiv((long)NN * 64, 256), 256, 0, stream>>>(emb[0], emb[1], emb[2], emb[3], out);
}

// Round 5
// 1509.285 us; speedup vs baseline: 1.1143x; 1.0290x over previous
//
#include <hip/hip_runtime.h>
#include <hip/hip_bf16.h>

// GraphEncoder: NNConv (edge-MLP 16->256->1024->1024 + einsum + scatter) + 3x GINConv.
// R12: 1553us. gemm256p (enn-L3) 121.4us = 754 TF, MfmaUtil 32%, conflicts 0.
// Diagnosis: QPHASE's forced lgkmcnt(0)+sched_barrier(0) serializes DS drain and
// MFMA (phase = drain + mfma, util = 154/500 = 31% -- matches). m97 evidence: the
// compiler emits fine-grained lgkmcnt(N) between ds_read and MFMA on its own;
// pinning lgkmcnt(0) defeats it (m141 lesson).
// R13: phase = {reads, [vmcnt(2) @ph4/8], ONE barrier, setprio+16 MFMA+setprio,
// stage}. No lgkmcnt(0), no sched_barrier -> first MFMA starts when its operands
// land; rest of the DS drain overlaps the MFMA cluster. Stage moved post-MFMA;
// full ledger re-derived: stage of region R >=1 barrier after all waves' reads of
// R retired; reads of R >=1 barrier after all waves' vmcnt confirm of R's loads.
// Prologue vmcnt(4); steady vmcnt(2)@ph4/ph8 (14->2, 10->2 outstanding).

#define NN 50000
#define EE 200000

typedef unsigned short u16;
typedef __attribute__((ext_vector_type(8))) short frag8;
typedef __attribute__((ext_vector_type(4))) float f32x4;

__device__ __forceinline__ float bf2f(u16 u) {
    union { unsigned int i; float f; } v; v.i = ((unsigned int)u) << 16; return v.f;
}
__device__ __forceinline__ u16 f2bf(float f) {
    union { float f; unsigned int i; } v; v.f = f;
    return (u16)((v.i + 0x7fffu + ((v.i >> 16) & 1u)) >> 16);
}
__device__ __forceinline__ float eluf(float v) {
    return v > 0.f ? v : __expf(v) - 1.f;
}

// ---------------- float dtype probe: fp32-as-bf16 shows crazy exponents ----------------
__global__ void probe_f32(const u16* __restrict__ raw, int* __restrict__ cnt) {
    int t = threadIdx.x;  // single block of 256
    int c = 0;
    for (int j = t; j < 1024; j += 256) {
        unsigned e = (raw[j] >> 7) & 0xFF;
        if (e >= 0xBF) c++;   // |v| >= 2^64: never in genuine N(0,1)-ish bf16 data
    }
    if (c) atomicAdd(cnt, c);
}
// dst bf16 <- src (fp32 if *cnt>=8 else bf16 passthrough)
__global__ void cvt_bf16(const void* __restrict__ src, u16* __restrict__ dst, long n,
                         const int* __restrict__ cnt) {
    long i = (long)blockIdx.x * 256 + threadIdx.x;
    if (i >= n) return;
    if (*cnt >= 8) dst[i] = f2bf(((const float*)src)[i]);
    else           dst[i] = ((const u16*)src)[i];
}

// ---------------- edge_index layout probe + conversion ----------------
__global__ void detect_idx64(const unsigned long long* __restrict__ p, int* __restrict__ flag) {
    long t = (long)blockIdx.x * 256 + threadIdx.x;
    if (t < EE) {
        unsigned long long v = p[t];
        if (v >> 31) atomicOr(flag, 1);   // int32-packed pairs have high bits set
    }
}
__global__ void convert_idx(const void* __restrict__ raw, const int* __restrict__ flag,
                            int* __restrict__ s_out, int* __restrict__ d_out) {
    long t = (long)blockIdx.x * 256 + threadIdx.x;
    if (t >= EE) return;
    if (*flag) {  // int32 layout
        const int* q = (const int*)raw;
        s_out[t] = q[t];
        d_out[t] = q[EE + t];
    } else {      // int64 layout
        const long long* q = (const long long*)raw;
        s_out[t] = (int)q[t];
        d_out[t] = (int)q[EE + t];
    }
}

// ---------------- generic bf16 transpose [K,N] -> [N,K] ----------------
__global__ void transpose_bf16(const u16* __restrict__ in, u16* __restrict__ out, int K, int N) {
    long idx = (long)blockIdx.x * 256 + threadIdx.x;
    if (idx < (long)K * N) {
        int k = (int)(idx / N);
        int n = (int)(idx % N);
        out[(long)n * K + k] = in[idx];
    }
}

// ---------------- edge MLP layer 1: h1 = ELU(attr @ W1 + b1), K=16, N=256 ----------------
__global__ void edge_mlp1(const u16* __restrict__ attr, const u16* __restrict__ w1,
                          const u16* __restrict__ b1, u16* __restrict__ h1, int ce) {
    __shared__ u16 sa[256];
    const int t = threadIdx.x;
    const int e0 = blockIdx.x * 16;
    const int cnt = min(16, ce - e0);
    sa[t] = (t < cnt * 16) ? attr[(long)e0 * 16 + t] : (u16)0;
    float w[16];
    #pragma unroll
    for (int i = 0; i < 16; ++i) w[i] = bf2f(w1[i * 256 + t]);
    const float bb = bf2f(b1[t]);
    __syncthreads();
    for (int e = 0; e < cnt; ++e) {
        float v = bb;
        #pragma unroll
        for (int i = 0; i < 16; ++i) v += bf2f(sa[e * 16 + i]) * w[i];
        h1[(long)(e0 + e) * 256 + t] = f2bf(eluf(v));
    }
}

// ---- stage 128x32 bf16 tile via global_load_lds (old 128^2 path, GIN g1/g2) ----
__device__ __forceinline__ void stage_tile(const u16* g, long row_base, long max_row,
                                           int kstride, int k0, u16* s, int t) {
    int wave = t >> 6;
    #pragma unroll
    for (int j = 0; j < 2; ++j) {
        int c = t + 256 * j;                 // chunk id 0..511 (16B each)
        long r = row_base + (c >> 2);        // 4 chunks per 32-elem row
        if (r > max_row) r = max_row;        // tail clamp (masked at C store)
        const u16* gp = g + r * (long)kstride + k0 + (c & 3) * 8;
        __builtin_amdgcn_global_load_lds(
            (__attribute__((address_space(1))) void*)(void*)gp,
            (__attribute__((address_space(3))) void*)((char*)s + wave * 1024 + j * 4096),
            16, 0, 0);                       // HW writes LDS at base + lane*16
    }
}

// C = ELU(A[M,K] @ BT[N,K]^T + bias), bf16 out. N mult of 128, K mult of 32.
// XCD-swizzled 1D grid. Kept for GIN g1/g2 (N=256, small FLOPs).
__global__ __launch_bounds__(256)
void gemm_bt_bias_elu(const u16* __restrict__ A, const u16* __restrict__ BT,
                      const u16* __restrict__ bias, u16* __restrict__ C,
                      int M, int K, int N, int mpx, int lognt) {
    const int bid = blockIdx.x;
    const int xcd = bid & 7;
    const int j = bid >> 3;
    const int m_idx = xcd * mpx + (j >> lognt);
    const int n_idx = j & ((1 << lognt) - 1);
    const int num_m = (M + 127) >> 7;
    if (m_idx >= num_m) return;              // block-uniform; before any barrier

    __shared__ __align__(16) u16 sA[128 * 32];
    __shared__ __align__(16) u16 sB[128 * 32];
    const int t = threadIdx.x;
    const int lane = t & 63;
    const int wave = t >> 6;
    const int wr = wave >> 1, wc = wave & 1;
    const int quad = lane >> 4, l16 = lane & 15;
    const long m0 = (long)m_idx * 128;
    const int n0 = n_idx * 128;

    f32x4 acc[4][4];
    const f32x4 z4 = {0.f, 0.f, 0.f, 0.f};
    #pragma unroll
    for (int mi = 0; mi < 4; ++mi)
        #pragma unroll
        for (int ni = 0; ni < 4; ++ni)
            acc[mi][ni] = z4;

    for (int k0 = 0; k0 < K; k0 += 32) {
        stage_tile(A, m0, (long)M - 1, K, k0, sA, t);
        stage_tile(BT, n0, (long)N - 1, K, k0, sB, t);
        __syncthreads();
        frag8 af[4], bfv[4];
        #pragma unroll
        for (int mi = 0; mi < 4; ++mi)
            af[mi] = *(const frag8*)(sA + (wr * 64 + mi * 16 + l16) * 32 + quad * 8);
        #pragma unroll
        for (int ni = 0; ni < 4; ++ni)
            bfv[ni] = *(const frag8*)(sB + (wc * 64 + ni * 16 + l16) * 32 + quad * 8);
        #pragma unroll
        for (int mi = 0; mi < 4; ++mi)
            #pragma unroll
            for (int ni = 0; ni < 4; ++ni)
                acc[mi][ni] = __builtin_amdgcn_mfma_f32_16x16x32_bf16(af[mi], bfv[ni], acc[mi][ni], 0, 0, 0);
        __syncthreads();
    }

    #pragma unroll
    for (int mi = 0; mi < 4; ++mi) {
        #pragma unroll
        for (int r = 0; r < 4; ++r) {
            long row = m0 + wr * 64 + mi * 16 + quad * 4 + r;  // C/D: row = quad*4+reg
            if (row < M) {
                #pragma unroll
                for (int ni = 0; ni < 4; ++ni) {
                    int col = n0 + wc * 64 + ni * 16 + l16;    // C/D: col = lane&15
                    float v = acc[mi][ni][r] + bf2f(bias[col]);
                    C[row * (long)N + col] = f2bf(eluf(v));
                }
            }
        }
    }
}

// ---------------- R13: 8-phase 256x256 GEMM (enn-L2/L3), BK=64 ----------------
// 512 thr = 8 waves (2M x 4N), per-wave out 128x64. LDS 128KB = buf{0,1} x
// regions {A0,A1,B0,B1} x 16KB. Each region: 128 rows x 64 k, row = 128B,
// 16B slots XOR-swizzled: LDS[row][s] holds global slot s^(row&7).
// Phase = {reads, [vmcnt(2) @ph4/8], barrier, setprio+16 MFMA+setprio, stage}.
// NO lgkmcnt(0)/sched_barrier: compiler emits fine-grained lgkm waits so the
// DS drain overlaps the MFMA cluster (m97/m141 lessons).
//
// Stage map (iter i; X=buf0 tile 2i, Y=buf1 2i+1; reads ph1-4 on X, ph5-8 on Y;
// stage runs AFTER the phase's MFMA, i.e., post-barrier):
//   ph1: st Y.A0<-t1   ph2: st Y.A1<-t1
//   ph3: st X.B0<-t2   ph4: vmcnt(2) pre-bar; st X.B1<-t2
//   ph5: st X.A0<-t2   ph6: st X.A1<-t2
//   ph7: st Y.B0<-t3   ph8: vmcnt(2) pre-bar; st Y.B1<-t3
// Race ledger: stage of region R is >=1 barrier after ALL waves' reads of R
// retired (reads retire before the consuming MFMA; MFMA precedes the wave's
// next barrier arrival). Reads of R are >=1 barrier after all waves' vmcnt
// confirming R's loads (vmcnt is pre-barrier). vmcnt(2)@ph4: outstanding
// [X.A0',X.A1',Y.B0',Y.B1',Y.A0,Y.A1,X.B0]=14 loads, newest Y = call 6/7 ->
// vmcnt(2) retires all Y. @ph8: [X.B0,X.B1,X.A0,X.A1,Y.B0]=10, newest X =
// call 4/5 -> vmcnt(2). Last iter: t2k/t3k clamp -> dead re-stages, safe.

#define QPHASE(PA, PB, QM, QN, LDA, LDB, VMW, STREG, SG, SRBASE, SRMAX, SKT)     \
  do {                                                                           \
    if (LDA) {                                                                   \
      _Pragma("unroll")                                                          \
      for (int mi = 0; mi < 4; ++mi) {                                           \
        _Pragma("unroll")                                                        \
        for (int kk = 0; kk < 2; ++kk) {                                         \
          int row = ((QM) * 4 + mi) * 16 + l16;                                  \
          int slot = ((kk << 2) + quad) ^ (l16 & 7);                             \
          av[mi][kk] = *(const frag8*)((const char*)(PA) + row * 128 + slot * 16); \
        }                                                                        \
      }                                                                          \
    }                                                                            \
    if ((LDB) >= 0) {                                                            \
      _Pragma("unroll")                                                          \
      for (int ni = 0; ni < 2; ++ni) {                                           \
        _Pragma("unroll")                                                        \
        for (int kk = 0; kk < 2; ++kk) {                                         \
          int row = (wn & 1) * 64 + (((LDB) & 1) * 2 + ni) * 16 + l16;           \
          int slot = ((kk << 2) + quad) ^ (l16 & 7);                             \
          bv[(LDB) & 1][ni][kk] =                                                \
              *(const frag8*)((const char*)(PB) + row * 128 + slot * 16);        \
        }                                                                        \
      }                                                                          \
    }                                                                            \
    if (VMW) asm volatile("s_waitcnt vmcnt(2)" ::: "memory");                    \
    __builtin_amdgcn_s_barrier();                                                \
    __builtin_amdgcn_s_setprio(1);                                               \
    _Pragma("unroll")                                                            \
    for (int kk = 0; kk < 2; ++kk) {                                             \
      _Pragma("unroll")                                                          \
      for (int mi = 0; mi < 4; ++mi) {                                           \
        _Pragma("unroll")                                                        \
        for (int ni = 0; ni < 2; ++ni) {                                         \
          acc[(QM) * 4 + mi][(QN) * 2 + ni] =                                    \
              __builtin_amdgcn_mfma_f32_16x16x32_bf16(                           \
                  av[mi][kk], bv[(QN)][ni][kk],                                  \
                  acc[(QM) * 4 + mi][(QN) * 2 + ni], 0, 0, 0);                   \
        }                                                                        \
      }                                                                          \
    }                                                                            \
    __builtin_amdgcn_s_setprio(0);                                               \
    stage((STREG), (SG), (SRBASE), (SRMAX), (SKT));                              \
  } while (0)

__global__ __launch_bounds__(512, 2)
void gemm256p(const u16* __restrict__ A, const u16* __restrict__ BT,
              const u16* __restrict__ bias, u16* __restrict__ C,
              int M, int K, int N, int mpx, int lognt) {
    const int bid = blockIdx.x;
    const int xcd = bid & 7;
    const int j = bid >> 3;
    const int m_idx = xcd * mpx + (j >> lognt);
    const int n_idx = j & ((1 << lognt) - 1);
    const int num_m = (M + 255) >> 8;
    if (m_idx >= num_m) return;              // block-uniform; before any barrier

    __shared__ __align__(16) u16 lds[2][4][8192];  // [buf][A0,A1,B0,B1][16KB]
    const int t = threadIdx.x;
    const int lane = t & 63;
    const int wave = t >> 6;          // 0..7
    const int wm = wave >> 2;         // 0..1 : M half (128 rows)
    const int wn = wave & 3;          // 0..3 : N quarter (64 cols)
    const int quad = lane >> 4, l16 = lane & 15;
    const long m0 = (long)m_idx * 256;
    const long n0 = (long)n_idx * 256;

    // staging: chunk ck = wave*2+jj covers 8 rows (1KB); lane -> row ck*8+(lane>>3),
    // LDS 16B-slot lane&7; GLOBAL slot pre-swizzled: g = (lane&7) ^ ((lane>>3)&7)
    // == slot ^ (row&7)  -> read at slot g^(row&7) finds global slot g.
    const int gslot = (((lane & 7) ^ ((lane >> 3) & 7)) << 3);  // elem offset

    auto stage = [&](u16* reg, const u16* G, long rbase, long rmax, int kt) {
        #pragma unroll
        for (int jj = 0; jj < 2; ++jj) {
            const int ck = wave * 2 + jj;
            long r = rbase + ck * 8 + (lane >> 3);
            if (r > rmax) r = rmax;          // tail clamp, masked at C store
            const u16* gp = G + r * (long)K + ((long)kt << 6) + gslot;
            __builtin_amdgcn_global_load_lds(
                (__attribute__((address_space(1))) void*)(void*)gp,
                (__attribute__((address_space(3))) void*)((char*)reg + ck * 1024),
                16, 0, 0);
        }
    };

    f32x4 acc[8][4];
    const f32x4 z4 = {0.f, 0.f, 0.f, 0.f};
    #pragma unroll
    for (int mi = 0; mi < 8; ++mi)
        #pragma unroll
        for (int ni = 0; ni < 4; ++ni)
            acc[mi][ni] = z4;
    frag8 av[4][2];        // current A quadrant (4 m-subtiles x 2 kk)
    frag8 bv[2][2][2];     // both B sets [qn][ni][kk]

    const int ntk = K >> 6;          // K multiple of 128 -> ntk even
    const int niter = ntk >> 1;
    const long MM = (long)M - 1, NMX = (long)N - 1;

    // prologue: X <- tile0 (4 regions = 8 loads, oldest), Y.B <- tile1 (4 loads).
    stage(&lds[0][2][0], BT, n0,       NMX, 0);
    stage(&lds[0][3][0], BT, n0 + 128, NMX, 0);
    stage(&lds[0][0][0], A,  m0,       MM,  0);
    stage(&lds[0][1][0], A,  m0 + 128, MM,  0);
    stage(&lds[1][2][0], BT, n0,       NMX, 1);
    stage(&lds[1][3][0], BT, n0 + 128, NMX, 1);
    asm volatile("s_waitcnt vmcnt(4)" ::: "memory");   // tile0's 8 loads landed
    __builtin_amdgcn_s_barrier();

    const u16* paX = &lds[0][wm][0];
    const u16* pbX = &lds[0][2 + (wn >> 1)][0];
    const u16* paY = &lds[1][wm][0];
    const u16* pbY = &lds[1][2 + (wn >> 1)][0];

    for (int it = 0; it < niter; ++it) {
        const int t1k = 2 * it + 1;
        int t2k = 2 * it + 2; if (t2k > ntk - 1) t2k = ntk - 1;
        int t3k = 2 * it + 3; if (t3k > ntk - 1) t3k = ntk - 1;

        QPHASE(paX, pbX, 0, 0, 1,  0, 0, &lds[1][0][0], A,  m0,       MM,  t1k);
        QPHASE(paX, pbX, 0, 1, 0,  1, 0, &lds[1][1][0], A,  m0 + 128, MM,  t1k);
        QPHASE(paX, pbX, 1, 0, 1, -1, 0, &lds[0][2][0], BT, n0,       NMX, t2k);
        QPHASE(paX, pbX, 1, 1, 0, -1, 1, &lds[0][3][0], BT, n0 + 128, NMX, t2k);
        QPHASE(paY, pbY, 0, 0, 1,  0, 0, &lds[0][0][0], A,  m0,       MM,  t2k);
        QPHASE(paY, pbY, 0, 1, 0,  1, 0, &lds[0][1][0], A,  m0 + 128, MM,  t2k);
        QPHASE(paY, pbY, 1, 0, 1, -1, 0, &lds[1][2][0], BT, n0,       NMX, t3k);
        QPHASE(paY, pbY, 1, 1, 0, -1, 1, &lds[1][3][0], BT, n0 + 128, NMX, t3k);
    }
    asm volatile("s_waitcnt vmcnt(0)" ::: "memory");   // drain leftover stages

    #pragma unroll
    for (int mi = 0; mi < 8; ++mi) {
        #pragma unroll
        for (int r = 0; r < 4; ++r) {
            long row = m0 + wm * 128 + mi * 16 + quad * 4 + r;   // C/D: row = quad*4+reg
            if (row < M) {
                #pragma unroll
                for (int ni = 0; ni < 4; ++ni) {
                    long col = n0 + wn * 64 + ni * 16 + l16;     // C/D: col = lane&15
                    float v = acc[mi][ni][r] + bf2f(bias[col]);
                    C[row * (long)N + col] = f2bf(eluf(v));
                }
            }
        }
    }
}

// C[M,64] fp32 = A[M,K] @ BT[64,K]^T + bias (no ELU). M-tile 256, N=64, K mult of 32.
__global__ __launch_bounds__(256)
void gemm_bt_f32(const u16* __restrict__ A, const u16* __restrict__ BT,
                 const u16* __restrict__ bias, float* __restrict__ C,
                 int M, int K) {
    __shared__ __align__(16) u16 sA[256 * 32];
    __shared__ __align__(16) u16 sB[64 * 32];
    const int t = threadIdx.x;
    const int lane = t & 63;
    const int wave = t >> 6;
    const int quad = lane >> 4, l16 = lane & 15;
    const long m0 = (long)blockIdx.x * 256;

    f32x4 acc[4][4];
    const f32x4 z4 = {0.f, 0.f, 0.f, 0.f};
    #pragma unroll
    for (int mi = 0; mi < 4; ++mi)
        #pragma unroll
        for (int ni = 0; ni < 4; ++ni)
            acc[mi][ni] = z4;

    for (int k0 = 0; k0 < K; k0 += 32) {
        #pragma unroll
        for (int j = 0; j < 4; ++j) {
            int c = t + 256 * j;
            long r = m0 + (c >> 2);
            if (r > (long)M - 1) r = (long)M - 1;
            const u16* gp = A + r * (long)K + k0 + (c & 3) * 8;
            __builtin_amdgcn_global_load_lds(
                (__attribute__((address_space(1))) void*)(void*)gp,
                (__attribute__((address_space(3))) void*)((char*)sA + wave * 1024 + j * 4096),
                16, 0, 0);
        }
        {
            int c = t;
            const u16* gp = BT + (long)(c >> 2) * K + k0 + (c & 3) * 8;
            __builtin_amdgcn_global_load_lds(
                (__attribute__((address_space(1))) void*)(void*)gp,
                (__attribute__((address_space(3))) void*)((char*)sB + wave * 1024),
                16, 0, 0);
        }
        __syncthreads();
        frag8 af[4], bfv[4];
        #pragma unroll
        for (int mi = 0; mi < 4; ++mi)
            af[mi] = *(const frag8*)(sA + (wave * 64 + mi * 16 + l16) * 32 + quad * 8);
        #pragma unroll
        for (int ni = 0; ni < 4; ++ni)
            bfv[ni] = *(const frag8*)(sB + (ni * 16 + l16) * 32 + quad * 8);
        #pragma unroll
        for (int mi = 0; mi < 4; ++mi)
            #pragma unroll
            for (int ni = 0; ni < 4; ++ni)
                acc[mi][ni] = __builtin_amdgcn_mfma_f32_16x16x32_bf16(af[mi], bfv[ni], acc[mi][ni], 0, 0, 0);
        __syncthreads();
    }

    #pragma unroll
    for (int mi = 0; mi < 4; ++mi) {
        #pragma unroll
        for (int r = 0; r < 4; ++r) {
            long row = m0 + wave * 64 + mi * 16 + quad * 4 + r;
            if (row < M) {
                #pragma unroll
                for (int ni = 0; ni < 4; ++ni) {
                    int col = ni * 16 + l16;
                    C[row * 64 + col] = acc[mi][ni][r] + bf2f(bias[col]);
                }
            }
        }
    }
}

// msg[e,o] = sum_i x[src[e],i] * we[e, i*64+o]; atomicAdd into agg[dst[e],o]
__global__ void nnconv_msg(const u16* __restrict__ we, const u16* __restrict__ x,
                           const int* __restrict__ src, const int* __restrict__ dst,
                           float* __restrict__ agg, int ce) {
    long idx = (long)blockIdx.x * 256 + threadIdx.x;
    if (idx >= (long)ce * 64) return;
    int o = (int)(idx & 63);
    long e = idx >> 6;
    const u16* wr = we + e * 1024;
    const u16* xr = x + (long)src[e] * 16;
    float v = 0.f;
    #pragma unroll
    for (int i = 0; i < 16; ++i)
        v += bf2f(xr[i]) * bf2f(wr[i * 64 + o]);
    atomicAdd(&agg[(long)dst[e] * 64 + o], v);
}

// ---- x_cur(emb0) = x @ root_w + root_b + agg (in-place on agg) ----
__global__ void add_root(const u16* __restrict__ x, const u16* __restrict__ rw,
                         const u16* __restrict__ rb, float* __restrict__ xcur) {
    long idx = (long)blockIdx.x * 256 + threadIdx.x;
    if (idx >= (long)NN * 64) return;
    int d = (int)(idx & 63);
    long n = idx >> 6;
    float v = bf2f(rb[d]);
    #pragma unroll
    for (int i = 0; i < 16; ++i)
        v += bf2f(x[n * 16 + i]) * bf2f(rw[i * 64 + d]);
    xcur[idx] += v;
}

__global__ void elu_bf16(const float* __restrict__ in, u16* __restrict__ o, long n) {
    long idx = (long)blockIdx.x * 256 + threadIdx.x;
    if (idx < n) o[idx] = f2bf(eluf(in[idx]));
}

__global__ void gin_scatter(const u16* __restrict__ xin, const int* __restrict__ src,
                            const int* __restrict__ dst, float* __restrict__ nbr) {
    long idx = (long)blockIdx.x * 256 + threadIdx.x;
    if (idx >= (long)EE * 64) return;
    int d = (int)(idx & 63);
    long e = idx >> 6;
    atomicAdd(&nbr[(long)dst[e] * 64 + d], bf2f(xin[(long)src[e] * 64 + d]));
}

__global__ void gin_combine(const u16* __restrict__ xin, const float* __restrict__ nbr,
                            u16* __restrict__ hin, long n) {
    long idx = (long)blockIdx.x * 256 + threadIdx.x;
    if (idx < n) hin[idx] = f2bf(bf2f(xin[idx]) + nbr[idx]);
}

// out[n,d,l] = emb_l[n*64+d] -- one float4 per (n,d), fully coalesced
__global__ void write_out(const float* __restrict__ e0, const float* __restrict__ e1,
                          const float* __restrict__ e2, const float* __restrict__ e3,
                          float* __restrict__ out) {
    long idx = (long)blockIdx.x * 256 + threadIdx.x;
    if (idx >= (long)NN * 64) return;
    float4 v = {e0[idx], e1[idx], e2[idx], e3[idx]};
    *(float4*)(out + idx * 4) = v;
}

extern "C" void kernel_launch(void* const* d_in, const int* in_sizes, int n_in,
                              void* d_out, int out_size, void* d_ws, size_t ws_size,
                              hipStream_t stream) {
    (void)in_sizes; (void)n_in; (void)out_size;
    const void* eidx = d_in[1];
    float* out = (float*)d_out;   // reference output dtype = float32

    char* ws = (char*)d_ws;
    size_t off = 0;
    auto alloc = [&](size_t bytes) {
        char* p = ws + off;
        off += (bytes + 255) & ~(size_t)255;
        return p;
    };
    // ---- persistent ----
    int* src32 = (int*)alloc((size_t)EE * 4);
    int* dst32 = (int*)alloc((size_t)EE * 4);
    int* flag  = (int*)alloc(256);
    int* cnt   = (int*)alloc(256);
    const int cv_idx[16] = {0, 2, 3, 4, 5, 6, 7, 8, 9, 10, 11, 12, 13, 14, 15, 16};
    const long cv_n[16]  = {800000, 3200000, 4096, 256, 262144, 1024, 1048576, 1024,
                            1024, 64, 49152, 768, 196608, 768, 49152, 192};
    u16* cv[16];
    for (int i = 0; i < 16; ++i) cv[i] = (u16*)alloc((size_t)cv_n[i] * 2);
    u16 *xc = cv[0], *eac = cv[1], *w1c = cv[2], *b1c = cv[3], *w2c = cv[4], *b2c = cv[5],
        *w3c = cv[6], *b3c = cv[7], *rwc = cv[8], *rbc = cv[9],
        *g1c = cv[10], *gb1c = cv[11], *g2c = cv[12], *gb2c = cv[13], *g3c = cv[14], *gb3c = cv[15];
    u16* w2t = (u16*)alloc((size_t)1024 * 256 * 2);
    u16* w3t = (u16*)alloc((size_t)1024 * 1024 * 2);
    u16* g1t = (u16*)alloc((size_t)3 * 256 * 64 * 2);
    u16* g2t = (u16*)alloc((size_t)3 * 256 * 256 * 2);
    u16* g3t = (u16*)alloc((size_t)3 * 64 * 256 * 2);
    // per-layer node embeddings, fp32 [N,64]; emb[0] doubles as agg/x_cur
    float* emb[4];
    for (int l = 0; l < 4; ++l) emb[l] = (float*)alloc((size_t)NN * 64 * 4);
    float* agg = emb[0];
    char* scratch = (char*)alloc(0);
    size_t avail = (ws_size > off + 4096) ? (ws_size - off - 4096) : 0;

    // ---- NNConv edge-chunk: h1c (512 B/e) + h2c (2048 B/e) + wec (2048 B/e) ----
    long CE = (long)(avail / 4608) & ~127L;
    if (CE < 128) CE = 128;
    if (CE > 200064) CE = 200064;
    u16* h1c = (u16*)scratch;
    u16* h2c = (u16*)(scratch + (size_t)CE * 512);
    u16* wec = (u16*)(scratch + (size_t)CE * 2560);

    // ---- GIN node-chunk: nbr+xin fixed (19.2MB) + 1152 B/node ----
    long gin_fixed = (long)NN * 64 * 4 + (long)NN * 64 * 2;
    long gin_avail = (long)avail - gin_fixed;
    if (gin_avail < 0) gin_avail = 0;
    long CN = (gin_avail / 1152) & ~255L;
    if (CN < 256) CN = 256;
    if (CN > 50176) CN = 50176;
    float* nbr = (float*)scratch;
    u16* xin   = (u16*)(scratch + (size_t)NN * 64 * 4);
    u16* hin   = (u16*)(scratch + gin_fixed);
    u16* hg1   = hin + (size_t)CN * 64;
    u16* hg2   = hg1 + (size_t)CN * 256;

    auto cdiv = [](long a, long b) { return (unsigned)((a + b - 1) / b); };

    // dtype probe on x, then normalize all float inputs to bf16
    hipMemsetAsync(cnt, 0, 4, stream);
    probe_f32<<<1, 256, 0, stream>>>((const u16*)d_in[0], cnt);
    for (int i = 0; i < 16; ++i)
        cvt_bf16<<<cdiv(cv_n[i], 256), 256, 0, stream>>>(d_in[cv_idx[i]], cv[i], cv_n[i], cnt);

    // edge_index conversion (layout-robust)
    hipMemsetAsync(flag, 0, 4, stream);
    detect_idx64<<<cdiv(EE, 256), 256, 0, stream>>>((const unsigned long long*)eidx, flag);
    convert_idx<<<cdiv(EE, 256), 256, 0, stream>>>(eidx, flag, src32, dst32);

    // weight transposes [K,N] -> [N,K]
    transpose_bf16<<<cdiv(256 * 1024, 256), 256, 0, stream>>>(w2c, w2t, 256, 1024);
    transpose_bf16<<<cdiv(1024 * 1024, 256), 256, 0, stream>>>(w3c, w3t, 1024, 1024);
    for (int l = 0; l < 3; ++l) {
        transpose_bf16<<<cdiv(64 * 256, 256), 256, 0, stream>>>(g1c + l * 64 * 256, g1t + l * 256 * 64, 64, 256);
        transpose_bf16<<<cdiv(256 * 256, 256), 256, 0, stream>>>(g2c + l * 256 * 256, g2t + l * 256 * 256, 256, 256);
        transpose_bf16<<<cdiv(256 * 64, 256), 256, 0, stream>>>(g3c + l * 256 * 64, g3t + l * 64 * 256, 256, 64);
    }

    // ---- NNConv (edge-chunked) ----
    hipMemsetAsync(agg, 0, (size_t)NN * 64 * 4, stream);
    for (long e0 = 0; e0 < EE; e0 += CE) {
        int ce = (int)((EE - e0 < CE) ? (EE - e0) : CE);
        int mpx2 = cdiv(cdiv(ce, 256), 8);
        edge_mlp1<<<cdiv(ce, 16), 256, 0, stream>>>(eac + e0 * 16, w1c, b1c, h1c, ce);
        gemm256p<<<8 * mpx2 * 4, 512, 0, stream>>>(h1c, w2t, b2c, h2c, ce, 256, 1024, mpx2, 2);
        gemm256p<<<8 * mpx2 * 4, 512, 0, stream>>>(h2c, w3t, b3c, wec, ce, 1024, 1024, mpx2, 2);
        nnconv_msg<<<cdiv((long)ce * 64, 256), 256, 0, stream>>>(wec, xc, src32 + e0, dst32 + e0, agg, ce);
    }
    add_root<<<cdiv((long)NN * 64, 256), 256, 0, stream>>>(xc, rwc, rbc, agg);

    // ---- 3x GINConv (node-chunked MLP) ----
    for (int l = 0; l < 3; ++l) {
        elu_bf16<<<cdiv((long)NN * 64, 256), 256, 0, stream>>>(emb[l], xin, (long)NN * 64);
        hipMemsetAsync(nbr, 0, (size_t)NN * 64 * 4, stream);
        gin_scatter<<<cdiv((long)EE * 64, 256), 256, 0, stream>>>(xin, src32, dst32, nbr);
        for (long n0 = 0; n0 < NN; n0 += CN) {
            int cn = (int)((NN - n0 < CN) ? (NN - n0) : CN);
            int mpx = cdiv(cdiv(cn, 128), 8);
            gin_combine<<<cdiv((long)cn * 64, 256), 256, 0, stream>>>(xin + n0 * 64, nbr + n0 * 64, hin, (long)cn * 64);
            gemm_bt_bias_elu<<<8 * mpx * 2, 256, 0, stream>>>(hin, g1t + l * 256 * 64, gb1c + l * 256, hg1, cn, 64, 256, mpx, 1);
            gemm_bt_bias_elu<<<8 * mpx * 2, 256, 0, stream>>>(hg1, g2t + l * 256 * 256, gb2c + l * 256, hg2, cn, 256, 256, mpx, 1);
            gemm_bt_f32<<<cdiv(cn, 256), 256, 0, stream>>>(hg2, g3t + l * 64 * 256, gb3c + l * 64, emb[l + 1] + n0 * 64, cn, 256);
        }
    }
    write_out<<<cdiv((long)NN * 64, 256), 256, 0, stream>>>(emb[0], emb[1], emb[2], emb[3], out);
}